// Round 1
// baseline (116.703 us; speedup 1.0000x reference)
//
#include <hip/hip_runtime.h>
#include <hip/hip_bf16.h>

typedef __attribute__((ext_vector_type(8))) __bf16 bf16x8;
typedef __attribute__((ext_vector_type(4))) float f32x4;
typedef unsigned short u16;

#define NB 8192
#define ND 128
#define NCHUNK 8

__device__ inline u16 f2b(float f){
  __hip_bfloat16 h = __float2bfloat16(f);
  return *reinterpret_cast<u16*>(&h);
}

// ---------------- prep: fp32 -> bf16, sq = ||x||^2, pinv = 1/(1-sq) ----------
extern "C" __global__ __launch_bounds__(256)
void prep_k(const float* __restrict__ x, u16* __restrict__ xb,
            float* __restrict__ sq, float* __restrict__ pinv)
{
  const int tid = blockIdx.x * 256 + threadIdx.x;
  const int row = tid >> 5;           // 32 threads per row
  const int sub = tid & 31;
  const float4 v = reinterpret_cast<const float4*>(x)[row * 32 + sub];
  float s = v.x*v.x + v.y*v.y + v.z*v.z + v.w*v.w;
  #pragma unroll
  for (int m = 1; m < 32; m <<= 1) s += __shfl_xor(s, m, 32);
  ushort4 o;
  o.x = f2b(v.x); o.y = f2b(v.y); o.z = f2b(v.z); o.w = f2b(v.w);
  reinterpret_cast<ushort4*>(xb)[row * 32 + sub] = o;
  if (sub == 0){ sq[row] = s; pinv[row] = 1.0f / (1.0f - s); }
}

// ---------------- main: bf16 MFMA gram tiles + streaming row max/min ---------
// grid (64, 8): blockIdx.x = 128-row tile, blockIdx.y = 1024-col chunk.
// 4 waves; wave w owns rows [R0+32w, R0+32w+32), all 128 cols of each col-tile.
extern "C" __global__ __launch_bounds__(256, 2)
void gram_k(const u16* __restrict__ xb, const float* __restrict__ sq,
            const float* __restrict__ pinv, const int* __restrict__ lab,
            float* __restrict__ ppos, float* __restrict__ pneg)
{
  __shared__ u16 Bt[128 * 128];   // 32 KB, 256B rows, 16B chunks XOR-swizzled by row&15
  const int wid  = threadIdx.x >> 6;
  const int lane = threadIdx.x & 63;
  const int m16  = lane & 15;
  const int quad = lane >> 4;
  const int R0 = blockIdx.x * 128;
  const int C0 = blockIdx.y * 1024;
  const int WR0 = R0 + wid * 32;

  // A fragments in registers: A[m=lane&15][k=quad*8+j], bytes = ks*64 + quad*16
  bf16x8 afrag[2][4];
  #pragma unroll
  for (int mt = 0; mt < 2; ++mt){
    const u16* arow = xb + (WR0 + mt*16 + m16) * ND;
    #pragma unroll
    for (int ks = 0; ks < 4; ++ks)
      afrag[mt][ks] = *reinterpret_cast<const bf16x8*>(arow + ks*32 + quad*8);
  }

  // per-row (C/D row = quad*4 + r) params
  float sqi[8]; int labi[8];
  #pragma unroll
  for (int mt = 0; mt < 2; ++mt)
    #pragma unroll
    for (int r = 0; r < 4; ++r){
      const int row = WR0 + mt*16 + quad*4 + r;
      sqi[mt*4+r]  = sq[row];
      labi[mt*4+r] = lab[row];
    }

  float vpos[8], vneg[8];
  #pragma unroll
  for (int i = 0; i < 8; ++i){ vpos[i] = -__builtin_inff(); vneg[i] = __builtin_inff(); }

  for (int ct = 0; ct < 8; ++ct){
    const int CT0 = C0 + ct * 128;
    __syncthreads();   // previous tile's ds_reads done before overwrite
    // stage B tile (128 rows x 256B) via global_load_lds, lane-linear dest.
    // LDS chunk position p of row j holds global chunk (p ^ (j&15)).
    #pragma unroll
    for (int c = 0; c < 8; ++c){
      const int cc   = wid * 8 + c;            // 1KB per call, 32 calls total
      const int brow = cc * 4 + (lane >> 4);
      const int src  = (lane & 15) ^ (brow & 15);
      const u16* gsrc = xb + (CT0 + brow) * ND + src * 8;
      __builtin_amdgcn_global_load_lds(
          (__attribute__((address_space(1))) void*)gsrc,
          (__attribute__((address_space(3))) void*)(Bt + cc * 512), 16, 0, 0);
    }
    __syncthreads();

    f32x4 acc[2][8];
    #pragma unroll
    for (int mt = 0; mt < 2; ++mt)
      #pragma unroll
      for (int nt = 0; nt < 8; ++nt){
        f32x4 z = {0.f, 0.f, 0.f, 0.f};
        acc[mt][nt] = z;
      }

    #pragma unroll
    for (int ks = 0; ks < 4; ++ks){
      const int t = ks * 4 + quad;             // 16B chunk index within row
      #pragma unroll
      for (int nt = 0; nt < 8; ++nt){
        const bf16x8 bfrag = *reinterpret_cast<const bf16x8*>(
            Bt + (nt*16 + m16) * 128 + ((t ^ m16) * 8));
        acc[0][nt] = __builtin_amdgcn_mfma_f32_16x16x32_bf16(afrag[0][ks], bfrag, acc[0][nt], 0, 0, 0);
        acc[1][nt] = __builtin_amdgcn_mfma_f32_16x16x32_bf16(afrag[1][ks], bfrag, acc[1][nt], 0, 0, 0);
      }
    }

    // epilogue: u = max(sq_i+sq_j-2g, 0)/(1-sq_j); masked running max/min
    #pragma unroll
    for (int nt = 0; nt < 8; ++nt){
      const int col  = CT0 + nt*16 + m16;
      const float sqj = sq[col];
      const float pj  = pinv[col];
      const int  labj = lab[col];
      #pragma unroll
      for (int mt = 0; mt < 2; ++mt){
        const bool tilediag = (WR0 + mt*16) == (CT0 + nt*16);
        #pragma unroll
        for (int r = 0; r < 4; ++r){
          const float g = acc[mt][nt][r];
          float u = fmaf(-2.0f, g, sqi[mt*4+r] + sqj);
          u = fmaxf(u, 0.0f) * pj;
          const bool same = (labi[mt*4+r] == labj);
          const bool dg   = tilediag && (m16 == quad*4 + r);
          const int idx = mt*4 + r;
          if (same && !dg) vpos[idx] = fmaxf(vpos[idx], u);
          if (!same)       vneg[idx] = fminf(vneg[idx], u);
        }
      }
    }
  }

  // row i lives in the 16 lanes of one quad-group: reduce across them
  #pragma unroll
  for (int i = 0; i < 8; ++i){
    #pragma unroll
    for (int m = 1; m < 16; m <<= 1){
      vpos[i] = fmaxf(vpos[i], __shfl_xor(vpos[i], m, 16));
      vneg[i] = fminf(vneg[i], __shfl_xor(vneg[i], m, 16));
    }
  }
  if (m16 == 0){
    #pragma unroll
    for (int i = 0; i < 8; ++i){
      const int row = WR0 + (i >> 2)*16 + quad*4 + (i & 3);
      ppos[blockIdx.y * NB + row] = vpos[i];
      pneg[blockIdx.y * NB + row] = vneg[i];
    }
  }
}

// ---------------- finalize: combine chunks, 2 arccosh per row, mean ----------
extern "C" __global__ __launch_bounds__(1024)
void finalize_k(const float* __restrict__ ppos, const float* __restrict__ pneg,
                const float* __restrict__ pinv, float* __restrict__ out)
{
  float lsum = 0.0f; int lcnt = 0;
  for (int row = threadIdx.x; row < NB; row += 1024){
    float up = -__builtin_inff(), un = __builtin_inff();
    #pragma unroll
    for (int c = 0; c < NCHUNK; ++c){
      up = fmaxf(up, ppos[c * NB + row]);
      un = fminf(un, pneg[c * NB + row]);
    }
    const bool hp = (up > -__builtin_inff());
    const bool hn = (un <  __builtin_inff());
    const float pi = pinv[row];
    float dp = 0.0f, dn = 0.0f;
    // arccosh(1+t) = log1p(t + sqrt(t*(t+2))), t clamped at 1e-7 (matches ref clamp)
    if (hp){ float t = fmaxf(2.0f * up * pi, 1e-7f); dp = log1pf(t + sqrtf(t * (t + 2.0f))); }
    if (hn){ float t = fmaxf(2.0f * un * pi, 1e-7f); dn = log1pf(t + sqrtf(t * (t + 2.0f))); }
    if (hp && hn){ lsum += fmaxf(dp - dn + 0.5f, 0.0f); lcnt++; }
  }
  #pragma unroll
  for (int m = 1; m < 64; m <<= 1){
    lsum += __shfl_xor(lsum, m, 64);
    lcnt += __shfl_xor(lcnt, m, 64);
  }
  __shared__ float s_sum[16];
  __shared__ int   s_cnt[16];
  const int w = threadIdx.x >> 6;
  if ((threadIdx.x & 63) == 0){ s_sum[w] = lsum; s_cnt[w] = lcnt; }
  __syncthreads();
  if (threadIdx.x == 0){
    float S = 0.0f; int C = 0;
    for (int i = 0; i < 16; ++i){ S += s_sum[i]; C += s_cnt[i]; }
    out[0] = (C > 0) ? (S / (float)C) : 0.0f;
  }
}

extern "C" void kernel_launch(void* const* d_in, const int* in_sizes, int n_in,
                              void* d_out, int out_size, void* d_ws, size_t ws_size,
                              hipStream_t stream)
{
  const float* x  = (const float*)d_in[0];
  const int* lab  = (const int*)d_in[1];
  char* ws = (char*)d_ws;
  u16*  xb   = (u16*)ws;                                   // 2 MB
  float* sq   = (float*)(ws + 2*1024*1024);                 // 32 KB
  float* pinv = (float*)(ws + 2*1024*1024 + 32*1024);       // 32 KB
  float* ppos = (float*)(ws + 2*1024*1024 + 64*1024);       // 256 KB
  float* pneg = (float*)(ws + 2*1024*1024 + 64*1024 + 256*1024); // 256 KB

  hipLaunchKernelGGL(prep_k, dim3(1024), dim3(256), 0, stream, x, xb, sq, pinv);
  hipLaunchKernelGGL(gram_k, dim3(64, NCHUNK), dim3(256), 0, stream,
                     xb, sq, pinv, lab, ppos, pneg);
  hipLaunchKernelGGL(finalize_k, dim3(1), dim3(1024), 0, stream, ppos, pneg, pinv, (float*)d_out);
}

// Round 2
// 102.292 us; speedup vs baseline: 1.1409x; 1.1409x over previous
//
#include <hip/hip_runtime.h>
#include <hip/hip_bf16.h>

typedef __attribute__((ext_vector_type(8))) __bf16 bf16x8;
typedef __attribute__((ext_vector_type(4))) float f32x4;
typedef unsigned short u16;

#define NB 8192
#define ND 128
#define NCHUNK 16
#define NEGINF (-__builtin_inff())
#define POSINF (__builtin_inff())

__device__ inline u16 f2b(float f){
  __hip_bfloat16 h = __float2bfloat16(f);
  return *reinterpret_cast<u16*>(&h);
}

// ---- prep: fp32 -> bf16, colp[row] = (sq, p=1/(1-sq), sq*p, lab_bits) ------
extern "C" __global__ __launch_bounds__(256)
void prep_k(const float* __restrict__ x, const int* __restrict__ lab,
            u16* __restrict__ xb, float4* __restrict__ colp)
{
  const int tid = blockIdx.x * 256 + threadIdx.x;
  const int row = tid >> 5;           // 32 threads per row
  const int sub = tid & 31;
  const float4 v = reinterpret_cast<const float4*>(x)[row * 32 + sub];
  float s = v.x*v.x + v.y*v.y + v.z*v.z + v.w*v.w;
  #pragma unroll
  for (int m = 1; m < 32; m <<= 1) s += __shfl_xor(s, m, 32);
  ushort4 o;
  o.x = f2b(v.x); o.y = f2b(v.y); o.z = f2b(v.z); o.w = f2b(v.w);
  reinterpret_cast<ushort4*>(xb)[row * 32 + sub] = o;
  if (sub == 0){
    const float p = 1.0f / (1.0f - s);
    colp[row] = make_float4(s, p, s * p, __int_as_float(lab[row]));
  }
}

// ---- main: bf16 MFMA gram tiles + streaming row max/min --------------------
// grid (64, 16): x = 128-row tile, y = 512-col chunk. 4 waves, each 32 rows.
extern "C" __global__ __launch_bounds__(256, 4)
void gram_k(const u16* __restrict__ xb, const float4* __restrict__ colp,
            float* __restrict__ ppos, float* __restrict__ pneg)
{
  __shared__ u16 Bt[128 * 128];   // 32 KB, 256B/row, 16B chunks XOR-swizzled by row&15
  const int wid  = threadIdx.x >> 6;
  const int lane = threadIdx.x & 63;
  const int m16  = lane & 15;
  const int quad = lane >> 4;
  const int R0  = blockIdx.x * 128;
  const int C0  = blockIdx.y * 512;
  const int WR0 = R0 + wid * 32;

  // A fragments in registers: A[m=lane&15][k=quad*8+j]
  bf16x8 afrag[2][4];
  #pragma unroll
  for (int mt = 0; mt < 2; ++mt){
    const u16* arow = xb + (WR0 + mt*16 + m16) * ND;
    #pragma unroll
    for (int ks = 0; ks < 4; ++ks)
      afrag[mt][ks] = *reinterpret_cast<const bf16x8*>(arow + ks*32 + quad*8);
  }

  // per-row (C/D row = quad*4 + r) params
  float sqi[8]; int labi[8];
  #pragma unroll
  for (int mt = 0; mt < 2; ++mt)
    #pragma unroll
    for (int r = 0; r < 4; ++r){
      const float4 cp = colp[WR0 + mt*16 + quad*4 + r];
      sqi[mt*4+r]  = cp.x;
      labi[mt*4+r] = __float_as_int(cp.w);
    }

  float vpos[8], vneg[8];
  #pragma unroll
  for (int i = 0; i < 8; ++i){ vpos[i] = NEGINF; vneg[i] = POSINF; }

  for (int ct = 0; ct < 4; ++ct){
    const int CT0 = C0 + ct * 128;
    __syncthreads();   // previous tile fully consumed before overwrite
    // stage B tile (128 rows x 256B) via global_load_lds, lane-linear dest.
    // LDS chunk position p of row j holds global chunk (p ^ (j&15)).
    #pragma unroll
    for (int c = 0; c < 8; ++c){
      const int cc   = wid * 8 + c;
      const int brow = cc * 4 + quad;
      const int src  = m16 ^ (brow & 15);
      const u16* gsrc = xb + (CT0 + brow) * ND + src * 8;
      __builtin_amdgcn_global_load_lds(
          (__attribute__((address_space(1))) void*)gsrc,
          (__attribute__((address_space(3))) void*)(Bt + cc * 512), 16, 0, 0);
    }
    __syncthreads();

    #pragma unroll
    for (int half = 0; half < 2; ++half){
      f32x4 acc[2][4];
      #pragma unroll
      for (int mt = 0; mt < 2; ++mt)
        #pragma unroll
        for (int nt4 = 0; nt4 < 4; ++nt4){
          f32x4 z = {0.f, 0.f, 0.f, 0.f};
          acc[mt][nt4] = z;
        }

      #pragma unroll
      for (int ks = 0; ks < 4; ++ks){
        const int t = ks * 4 + quad;             // 16B chunk index within row
        #pragma unroll
        for (int nt4 = 0; nt4 < 4; ++nt4){
          const int nt = half * 4 + nt4;
          const bf16x8 bfrag = *reinterpret_cast<const bf16x8*>(
              Bt + (nt*16 + m16) * 128 + ((t ^ m16) * 8));
          acc[0][nt4] = __builtin_amdgcn_mfma_f32_16x16x32_bf16(afrag[0][ks], bfrag, acc[0][nt4], 0, 0, 0);
          acc[1][nt4] = __builtin_amdgcn_mfma_f32_16x16x32_bf16(afrag[1][ks], bfrag, acc[1][nt4], 0, 0, 0);
        }
      }

      // epilogue: u = (sq_i + sq_j - 2g) * p_j  (no interior clamp; finalize clamps)
      #pragma unroll
      for (int nt4 = 0; nt4 < 4; ++nt4){
        const int nt  = half * 4 + nt4;
        const float4 cp = colp[CT0 + nt*16 + m16];
        const float pj   = cp.y;
        const float spj  = cp.z;
        const int   labj = __float_as_int(cp.w);
        const float n2pj = -2.0f * pj;
        #pragma unroll
        for (int mt = 0; mt < 2; ++mt){
          const bool tilediag = (WR0 + mt*16) == (CT0 + nt*16);
          if (!tilediag){
            #pragma unroll
            for (int r = 0; r < 4; ++r){
              const int idx = mt*4 + r;
              const float u = fmaf(n2pj, acc[mt][nt4][r], fmaf(sqi[idx], pj, spj));
              const bool sm = (labi[idx] == labj);
              vpos[idx] = fmaxf(vpos[idx], sm ? u : NEGINF);
              vneg[idx] = fminf(vneg[idx], sm ? POSINF : u);
            }
          } else {
            #pragma unroll
            for (int r = 0; r < 4; ++r){
              const int idx = mt*4 + r;
              const float u = fmaf(n2pj, acc[mt][nt4][r], fmaf(sqi[idx], pj, spj));
              const bool sm = (labi[idx] == labj);
              const bool dg = (m16 == quad*4 + r);
              vpos[idx] = fmaxf(vpos[idx], (sm && !dg) ? u : NEGINF);
              vneg[idx] = fminf(vneg[idx], sm ? POSINF : u);
            }
          }
        }
      }
    }
  }

  // row i lives in the 16 lanes of one quad-group: reduce across them
  #pragma unroll
  for (int i = 0; i < 8; ++i){
    #pragma unroll
    for (int m = 1; m < 16; m <<= 1){
      vpos[i] = fmaxf(vpos[i], __shfl_xor(vpos[i], m, 16));
      vneg[i] = fminf(vneg[i], __shfl_xor(vneg[i], m, 16));
    }
  }
  if (m16 == 0){
    #pragma unroll
    for (int i = 0; i < 8; ++i){
      const int row = WR0 + (i >> 2)*16 + quad*4 + (i & 3);
      ppos[blockIdx.y * NB + row] = vpos[i];
      pneg[blockIdx.y * NB + row] = vneg[i];
    }
  }
}

// ---- finalize stage 1: 64 blocks x 128 rows -> per-block (sum, cnt) --------
extern "C" __global__ __launch_bounds__(128)
void fin1_k(const float* __restrict__ ppos, const float* __restrict__ pneg,
            const float4* __restrict__ colp, float2* __restrict__ bpart)
{
  const int row = blockIdx.x * 128 + threadIdx.x;
  float up = NEGINF, un = POSINF;
  #pragma unroll
  for (int c = 0; c < NCHUNK; ++c){
    up = fmaxf(up, ppos[c * NB + row]);
    un = fminf(un, pneg[c * NB + row]);
  }
  const bool hp = (up > NEGINF);
  const bool hn = (un < POSINF);
  const float pi = colp[row].y;
  float dp = 0.0f, dn = 0.0f;
  // arccosh(1+t) = log1p(t + sqrt(t*(t+2))), t clamped at 1e-7 (matches ref)
  if (hp){ float t = fmaxf(2.0f * up * pi, 1e-7f); dp = log1pf(t + sqrtf(t * (t + 2.0f))); }
  if (hn){ float t = fmaxf(2.0f * un * pi, 1e-7f); dn = log1pf(t + sqrtf(t * (t + 2.0f))); }
  float lsum = (hp && hn) ? fmaxf(dp - dn + 0.5f, 0.0f) : 0.0f;
  float lcnt = (hp && hn) ? 1.0f : 0.0f;
  #pragma unroll
  for (int m = 1; m < 64; m <<= 1){
    lsum += __shfl_xor(lsum, m, 64);
    lcnt += __shfl_xor(lcnt, m, 64);
  }
  __shared__ float2 s_p[2];
  if ((threadIdx.x & 63) == 0) s_p[threadIdx.x >> 6] = make_float2(lsum, lcnt);
  __syncthreads();
  if (threadIdx.x == 0){
    bpart[blockIdx.x] = make_float2(s_p[0].x + s_p[1].x, s_p[0].y + s_p[1].y);
  }
}

// ---- finalize stage 2: one wave reduces 64 partials ------------------------
extern "C" __global__ __launch_bounds__(64)
void fin2_k(const float2* __restrict__ bpart, float* __restrict__ out)
{
  float2 p = bpart[threadIdx.x];
  float s = p.x, c = p.y;
  #pragma unroll
  for (int m = 1; m < 64; m <<= 1){
    s += __shfl_xor(s, m, 64);
    c += __shfl_xor(c, m, 64);
  }
  if (threadIdx.x == 0) out[0] = (c > 0.0f) ? (s / c) : 0.0f;
}

extern "C" void kernel_launch(void* const* d_in, const int* in_sizes, int n_in,
                              void* d_out, int out_size, void* d_ws, size_t ws_size,
                              hipStream_t stream)
{
  const float* x  = (const float*)d_in[0];
  const int* lab  = (const int*)d_in[1];
  char* ws = (char*)d_ws;
  u16*    xb   = (u16*)ws;                                        // 2 MB
  float4* colp = (float4*)(ws + (size_t)2*1024*1024);             // 128 KB
  float*  ppos = (float*)(ws + (size_t)2*1024*1024 + 128*1024);   // 512 KB
  float*  pneg = (float*)(ws + (size_t)2*1024*1024 + 128*1024 + 512*1024); // 512 KB
  float2* bpart= (float2*)(ws + (size_t)2*1024*1024 + 128*1024 + 1024*1024); // 512 B

  hipLaunchKernelGGL(prep_k, dim3(1024), dim3(256), 0, stream, x, lab, xb, colp);
  hipLaunchKernelGGL(gram_k, dim3(64, NCHUNK), dim3(256), 0, stream,
                     xb, colp, ppos, pneg);
  hipLaunchKernelGGL(fin1_k, dim3(64), dim3(128), 0, stream, ppos, pneg, colp, bpart);
  hipLaunchKernelGGL(fin2_k, dim3(1), dim3(64), 0, stream, bpart, (float*)d_out);
}